// Round 6
// baseline (233.535 us; speedup 1.0000x reference)
//
#include <hip/hip_runtime.h>
#include <math.h>

#define T_SEQ   2048
#define DMODEL  512
#define NHEADS  8
#define DH      64
#define NEG_INF -1.0e9f

typedef __attribute__((ext_vector_type(8))) short short8;
typedef __attribute__((ext_vector_type(4))) float f32x4;
typedef unsigned int u32;
typedef unsigned short u16;

// cheap bf16 pack: round-half-up, error <= 2^-9 rel. No NaNs in this pipeline.
__device__ __forceinline__ u16 f2bf(float f) {
    union { float f; u32 u; } w; w.f = f;
    return (u16)((w.u + 0x8000u) >> 16);
}

// ---------------------------------------------------------------------------
// fused fp32->bf16 casts (x + 4 weights) + span-loss scalar. 5120 blocks.
// ---------------------------------------------------------------------------
__global__ void cast_all(const float* __restrict__ x,  const float* __restrict__ wq,
                         const float* __restrict__ wk, const float* __restrict__ wv,
                         const float* __restrict__ wo, const float* __restrict__ sp,
                         u16* __restrict__ xb,  u16* __restrict__ wqb,
                         u16* __restrict__ wkb, u16* __restrict__ wvb,
                         u16* __restrict__ wob, float* __restrict__ loss_out)
{
    const int bid = blockIdx.x;
    const float* src; u16* dst; int i;
    if (bid < 4096) { src = x; dst = xb; i = bid * 256 + threadIdx.x; }
    else {
        const int wsel = (bid - 4096) >> 8;
        src = (wsel == 0) ? wq : (wsel == 1) ? wk : (wsel == 2) ? wv : wo;
        dst = (wsel == 0) ? wqb : (wsel == 1) ? wkb : (wsel == 2) ? wvb : wob;
        i = ((bid - 4096) & 255) * 256 + threadIdx.x;
    }
    float4 v = ((const float4*)src)[i];
    ushort4 o;
    o.x = f2bf(v.x); o.y = f2bf(v.y); o.z = f2bf(v.z); o.w = f2bf(v.w);
    ((ushort4*)dst)[i] = o;
    if (bid == 5119 && threadIdx.x == 0) {
        float s = 0.0f;
        for (int h = 0; h < NHEADS; ++h)
            s += fminf(fmaxf(sp[h], 0.0f), 1.0f);
        loss_out[0] = 2e-4f * (s * 0.125f);
    }
}

// ---------------------------------------------------------------------------
// bf16 MFMA GEMM with register-prefetch double buffer: next K-tile is loaded
// into VGPRs while MFMAs run; ds_write after the barrier (loads stay in
// flight across the barrier - no global_load_lds drain).
// z=0/1: bf16 (B,H,T,DH); z=2: bf16 (B,H,DH,T) (V^T); scatter=0: fp32 M x 512.
// ---------------------------------------------------------------------------
__global__ __launch_bounds__(256, 3)
void gemm_bf16(const u16* __restrict__ A,
               const u16* __restrict__ W0, const u16* __restrict__ W1,
               const u16* __restrict__ W2,
               u16* __restrict__ Cb0, u16* __restrict__ Cb1,
               u16* __restrict__ Cb2,
               float* __restrict__ Cf, int scatter)
{
    constexpr int K = 512, BK = 64;
    const u16* W  = (blockIdx.z == 0) ? W0 : (blockIdx.z == 1) ? W1 : W2;
    u16*       Cb = (blockIdx.z == 0) ? Cb0 : (blockIdx.z == 1) ? Cb1 : Cb2;

    __shared__ __align__(16) u16 smem[16384];   // 32 KB: As|Bs, reused by epilogue
    u16* As = smem;
    u16* Bs = smem + 8192;

    const int t    = threadIdx.x;
    const int lane = t & 63;
    const int wave = t >> 6;
    const int wm   = wave >> 1, wn = wave & 1;
    const int m0   = blockIdx.x * 128, n0 = blockIdx.y * 128;

    const int srow = t >> 3;
    const int kb   = (t & 7) ^ (srow & 7);
    const u16* gA = A + (size_t)(m0 + srow) * K + kb * 8;
    const u16* gW = W + (size_t)(n0 + srow) * K + kb * 8;

    const int rA = wm * 64 + (lane & 15);
    const int rB = wn * 64 + (lane & 15);
    const int kq = lane >> 4;
    const int offA0 = rA * BK + ((kq      ^ (rA & 7)) * 8);
    const int offA1 = rA * BK + (((4 + kq) ^ (rA & 7)) * 8);
    const int offB0 = rB * BK + ((kq      ^ (rB & 7)) * 8);
    const int offB1 = rB * BK + (((4 + kq) ^ (rB & 7)) * 8);

    f32x4 acc[4][4];
#pragma unroll
    for (int it = 0; it < 4; ++it)
#pragma unroll
        for (int jt = 0; jt < 4; ++jt) acc[it][jt] = (f32x4)0.0f;

    // prologue: prefetch tile 0 into registers
    uint4 ar[4], wr[4];
#pragma unroll
    for (int i = 0; i < 4; ++i) {
        ar[i] = *(const uint4*)(gA + i * (32 * K));
        wr[i] = *(const uint4*)(gW + i * (32 * K));
    }

    for (int k0 = 0; k0 < K; k0 += BK) {
        __syncthreads();               // prior compute done (LDS reuse safe)
#pragma unroll
        for (int i = 0; i < 4; ++i) {
            *(uint4*)(As + t * 8 + i * 2048) = ar[i];
            *(uint4*)(Bs + t * 8 + i * 2048) = wr[i];
        }
        __syncthreads();               // tile visible

        if (k0 + BK < K) {             // prefetch next tile (in flight across barrier)
#pragma unroll
            for (int i = 0; i < 4; ++i) {
                ar[i] = *(const uint4*)(gA + (k0 + BK) + i * (32 * K));
                wr[i] = *(const uint4*)(gW + (k0 + BK) + i * (32 * K));
            }
        }

        short8 af[4][2], bfr[4][2];
#pragma unroll
        for (int it = 0; it < 4; ++it) {
            af[it][0]  = *(const short8*)(As + offA0 + it * 16 * BK);
            af[it][1]  = *(const short8*)(As + offA1 + it * 16 * BK);
            bfr[it][0] = *(const short8*)(Bs + offB0 + it * 16 * BK);
            bfr[it][1] = *(const short8*)(Bs + offB1 + it * 16 * BK);
        }
#pragma unroll
        for (int it = 0; it < 4; ++it)
#pragma unroll
            for (int jt = 0; jt < 4; ++jt) {
                acc[it][jt] = __builtin_amdgcn_mfma_f32_16x16x32_bf16(
                    af[it][0], bfr[jt][0], acc[it][jt], 0, 0, 0);
                acc[it][jt] = __builtin_amdgcn_mfma_f32_16x16x32_bf16(
                    af[it][1], bfr[jt][1], acc[it][jt], 0, 0, 0);
            }
    }

    const int r0 = (lane >> 4) * 4;
    const int cl = lane & 15;

    if (scatter) {
        const bool vt_mode = (blockIdx.z == 2);
        constexpr int P = 136;
#pragma unroll
        for (int rnd = 0; rnd < 2; ++rnd) {
            __syncthreads();
#pragma unroll
            for (int s = 0; s < 2; ++s) {
                const int it = rnd * 2 + s;
                const int lrow = wm * 32 + s * 16 + r0;
#pragma unroll
                for (int jt = 0; jt < 4; ++jt) {
                    const int cc = wn * 64 + jt * 16 + cl;
#pragma unroll
                    for (int r = 0; r < 4; ++r)
                        smem[(lrow + r) * P + cc] = f2bf(acc[it][jt][r]);
                }
            }
            __syncthreads();
            if (!vt_mode) {
                const int lrow2 = t >> 2;
                const int h2    = (t >> 1) & 1;
                const int dhalf = t & 1;
                const int grow  = m0 + (lrow2 >> 5) * 64 + rnd * 32 + (lrow2 & 31);
                const int b     = grow >> 11, tt = grow & 2047;
                const int h     = (n0 >> 6) + h2;
                u16* dst = Cb + ((size_t)((b * NHEADS + h) * T_SEQ + tt)) * DH + dhalf * 32;
                const u16* srcl = smem + lrow2 * P + h2 * 64 + dhalf * 32;
#pragma unroll
                for (int i = 0; i < 4; ++i)
                    ((uint4*)dst)[i] = *(const uint4*)(srcl + i * 8);
            } else {
                const int hd   = t >> 1;
                const int run  = t & 1;
                const int h    = (n0 >> 6) + (hd >> 6);
                const int d    = hd & 63;
                const int tb   = m0 + run * 64 + rnd * 32;
                const int b    = tb >> 11;
                u16* dst = Cb + (((size_t)(b * NHEADS + h) * DH + d) << 11) + (tb & 2047);
                union { uint4 v[4]; u16 s[32]; } pk;
#pragma unroll
                for (int i = 0; i < 32; ++i)
                    pk.s[i] = smem[(run * 32 + i) * P + hd];
#pragma unroll
                for (int i = 0; i < 4; ++i)
                    ((uint4*)dst)[i] = pk.v[i];
            }
        }
    } else {
#pragma unroll
        for (int it = 0; it < 4; ++it) {
#pragma unroll
            for (int r = 0; r < 4; ++r) {
                const int row = m0 + wm * 64 + it * 16 + r0 + r;
#pragma unroll
                for (int jt = 0; jt < 4; ++jt) {
                    const int col = n0 + wn * 64 + jt * 16 + cl;
                    Cf[(size_t)row * DMODEL + col] = acc[it][jt][r];
                }
            }
        }
    }
}

// ---------------------------------------------------------------------------
// Barrier-free MFMA windowed flash attention. One WAVE = one 16-query tile.
// K/V MFMA B-fragments loaded DIRECTLY from global (L2-resident via XCD pin);
// only P round-trips through private LDS (in-wave, no __syncthreads anywhere).
// Grid (32, 128): x -> (b = x>>3, h = ((x&7)+5b)&7) so each XCD (linear%8)
// serves 4 fixed (b,h) pairs (2 MB K+V in its 4 MB L2), mixed head parity.
// Q,K in (B,H,T,DH); Vt in (B,H,DH,T); out bf16 (B,T,DMODEL).
// ---------------------------------------------------------------------------
__global__ __launch_bounds__(64, 4)
void attn_wave(const u16* __restrict__ Q, const u16* __restrict__ K,
               const u16* __restrict__ Vt, const float* __restrict__ span_params,
               u16* __restrict__ out)
{
    __shared__ __align__(16) u16 Ps[16 * 72];   // P [q][key], pitch 72

    const int lane = threadIdx.x;
    const int nl   = lane & 15;
    const int quad = lane >> 4;
    const int xi   = blockIdx.x;
    const int b    = xi >> 3;
    const int h    = ((xi & 7) + 5 * b) & 7;
    const int bh   = b * NHEADS + h;
    const int q0   = blockIdx.y * 16;

    const u16* Qh = Q  + (size_t)bh * (T_SEQ * DH);
    const u16* Kh = K  + (size_t)bh * (T_SEQ * DH);
    const u16* Vh = Vt + (size_t)bh * (DH * T_SEQ);

    float span = span_params[h];
    span = fminf(fmaxf(span, 0.0f), 1.0f);
    const float eff_span = span * 512.0f;
    const int wspan = (int)(eff_span + 1.0f) + 1;

    // Q A-fragments in registers for the whole kernel
    short8 qf0 = *(const short8*)(Qh + (size_t)(q0 + nl) * DH + quad * 8);
    short8 qf1 = *(const short8*)(Qh + (size_t)(q0 + nl) * DH + 32 + quad * 8);

    f32x4 o[4];
    float m_r[4], l_r[4];
#pragma unroll
    for (int d = 0; d < 4; ++d) o[d] = (f32x4)0.0f;
#pragma unroll
    for (int r = 0; r < 4; ++r) { m_r[r] = -1.0e30f; l_r[r] = 0.0f; }

    int j_lo = q0 - wspan;
    if (j_lo < 0) j_lo = 0;
    j_lo &= ~63;
    const int j_hi = (q0 + 15) & ~63;

    for (int j0 = j_lo; j0 <= j_hi; j0 += 64) {
        // ---- tile activity (wave-uniform) ----
        bool any[4];
#pragma unroll
        for (int n = 0; n < 4; ++n) {
            const int jn = j0 + n * 16;
            any[n] = (jn <= q0 + 15) &&
                     ((float)(q0 - jn - 15) < eff_span + 1.0f);   // some R>0
        }

        // ---- S = Q K^T: B-frags straight from global ----
        f32x4 s[4];
#pragma unroll
        for (int n = 0; n < 4; ++n) {
            s[n] = (f32x4)0.0f;
            if (any[n]) {
                const u16* kp = Kh + (size_t)(j0 + n * 16 + nl) * DH + quad * 8;
                short8 b0 = *(const short8*)kp;
                short8 b1 = *(const short8*)(kp + 32);
                s[n] = __builtin_amdgcn_mfma_f32_16x16x32_bf16(qf0, b0, s[n], 0, 0, 0);
                s[n] = __builtin_amdgcn_mfma_f32_16x16x32_bf16(qf1, b1, s[n], 0, 0, 0);
            }
        }

        // ---- V B-frags: issue early so latency hides behind softmax ----
        const bool kf0 = any[0] | any[1];
        const bool kf1 = any[2] | any[3];
        short8 vb0[4], vb1[4];
#pragma unroll
        for (int d = 0; d < 4; ++d) {
            const u16* vp = Vh + (size_t)(d * 16 + nl) * T_SEQ + j0 + quad * 8;
            if (kf0) vb0[d] = *(const short8*)vp;
            if (kf1) vb1[d] = *(const short8*)(vp + 32);
        }

        // ---- mask + row max, 3-way tile classification (wave-uniform) ----
        float tmax[4] = {-1.0e30f, -1.0e30f, -1.0e30f, -1.0e30f};
#pragma unroll
        for (int n = 0; n < 4; ++n) {
            if (!any[n]) continue;
            const int jn = j0 + n * 16;
            const bool causal_b = (jn + 15 > q0);
            const bool span_b   = ((float)(q0 + 15 - jn) > eff_span - 3.0f);
            if (!causal_b && !span_b) {
#pragma unroll
                for (int r = 0; r < 4; ++r) {
                    const float sv = s[n][r] * 0.125f;
                    s[n][r] = sv;
                    tmax[r] = fmaxf(tmax[r], sv);
                }
            } else if (!span_b) {
#pragma unroll
                for (int r = 0; r < 4; ++r) {
                    const int dist = (q0 + quad * 4 + r) - (jn + nl);
                    const float sv = (dist >= 0) ? s[n][r] * 0.125f : NEG_INF;
                    s[n][r] = sv;
                    tmax[r] = fmaxf(tmax[r], sv);
                }
            } else {
#pragma unroll
                for (int r = 0; r < 4; ++r) {
                    const int dist = (q0 + quad * 4 + r) - (jn + nl);
                    float sv = NEG_INF;
                    if (dist >= 0) {
                        float xv = eff_span - (float)dist;
                        float R  = fminf(fmaxf((xv + 1.0f) * 0.25f, 0.0f), 1.0f);
                        if (R > 0.0f)
                            sv = s[n][r] * 0.125f +
                                 ((R < 1.0f) ? __logf(R + 1e-10f) : 0.0f);
                    }
                    s[n][r] = sv;
                    tmax[r] = fmaxf(tmax[r], sv);
                }
            }
        }

        // ---- online softmax state ----
        float alpha[4];
#pragma unroll
        for (int r = 0; r < 4; ++r) {
            float t = tmax[r];
            t = fmaxf(t, __shfl_xor(t, 1));
            t = fmaxf(t, __shfl_xor(t, 2));
            t = fmaxf(t, __shfl_xor(t, 4));
            t = fmaxf(t, __shfl_xor(t, 8));
            const float m_new = fmaxf(m_r[r], t);
            alpha[r] = __expf(m_r[r] - m_new);
            m_r[r] = m_new;
        }

        // ---- P = exp(S - m) -> bf16 LDS (in-wave round trip, no barrier) ----
        float psum[4] = {0.0f, 0.0f, 0.0f, 0.0f};
#pragma unroll
        for (int n = 0; n < 4; ++n) {
            if (any[n]) {
#pragma unroll
                for (int r = 0; r < 4; ++r) {
                    const float pv = __expf(s[n][r] - m_r[r]);
                    psum[r] += pv;
                    Ps[(quad * 4 + r) * 72 + n * 16 + nl] = f2bf(pv);
                }
            } else {
#pragma unroll
                for (int r = 0; r < 4; ++r)
                    Ps[(quad * 4 + r) * 72 + n * 16 + nl] = 0;
            }
        }
#pragma unroll
        for (int r = 0; r < 4; ++r) {
            float ps = psum[r];
            ps += __shfl_xor(ps, 1);
            ps += __shfl_xor(ps, 2);
            ps += __shfl_xor(ps, 4);
            ps += __shfl_xor(ps, 8);
            l_r[r] = l_r[r] * alpha[r] + ps;
#pragma unroll
            for (int d = 0; d < 4; ++d) o[d][r] *= alpha[r];
        }

        // ---- O += P V ----
        const u16* pb = Ps + nl * 72;
        short8 a0 = *(const short8*)(pb + quad * 8);
        short8 a1 = *(const short8*)(pb + 32 + quad * 8);
#pragma unroll
        for (int d = 0; d < 4; ++d) {
            if (kf0)
                o[d] = __builtin_amdgcn_mfma_f32_16x16x32_bf16(a0, vb0[d], o[d], 0, 0, 0);
            if (kf1)
                o[d] = __builtin_amdgcn_mfma_f32_16x16x32_bf16(a1, vb1[d], o[d], 0, 0, 0);
        }
    }

    // ---- epilogue ----
#pragma unroll
    for (int r = 0; r < 4; ++r) {
        const int qg = q0 + quad * 4 + r;
        const float inv_l = 1.0f / l_r[r];
        u16* op = out + (size_t)(b * T_SEQ + qg) * DMODEL + h * 64;
#pragma unroll
        for (int d = 0; d < 4; ++d)
            op[d * 16 + nl] = f2bf(o[d][r] * inv_l);
    }
}

extern "C" void kernel_launch(void* const* d_in, const int* in_sizes, int n_in,
                              void* d_out, int out_size, void* d_ws, size_t ws_size,
                              hipStream_t stream)
{
    (void)in_sizes; (void)n_in; (void)out_size; (void)ws_size;
    const float* x  = (const float*)d_in[0];
    const float* wq = (const float*)d_in[1];
    const float* wk = (const float*)d_in[2];
    const float* wv = (const float*)d_in[3];
    const float* wo = (const float*)d_in[4];
    const float* sp = (const float*)d_in[5];
    float* out = (float*)d_out;

    const size_t elems = (size_t)4 * T_SEQ * DMODEL;  // 4,194,304
    u16* xb  = (u16*)d_ws;
    u16* Qb  = xb  + elems;
    u16* Kb  = Qb  + elems;
    u16* Vtb = Kb  + elems;
    u16* Ab  = Vtb + elems;
    u16* wqb = Ab  + elems;
    u16* wkb = wqb + 262144;
    u16* wvb = wkb + 262144;
    u16* wob = wvb + 262144;

    // casts + loss (one launch)
    cast_all<<<5120, 256, 0, stream>>>(x, wq, wk, wv, wo, sp,
                                       xb, wqb, wkb, wvb, wob, out + elems);
    // Q,K,V projections (V written directly transposed), reg-prefetch dbuf
    gemm_bf16<<<dim3(64, 4, 3), 256, 0, stream>>>(
        xb, wqb, wkb, wvb, Qb, Kb, Vtb, nullptr, 1);
    // barrier-free MFMA windowed flash attention (1 wave = 16 q)
    attn_wave<<<dim3(32, 128), 64, 0, stream>>>(Qb, Kb, Vtb, sp, Ab);
    // output projection (fp32 out)
    gemm_bf16<<<dim3(64, 4, 1), 256, 0, stream>>>(
        Ab, wob, wob, wob, nullptr, nullptr, nullptr, out, 0);
}

// Round 7
// 176.426 us; speedup vs baseline: 1.3237x; 1.3237x over previous
//
#include <hip/hip_runtime.h>
#include <math.h>

#define T_SEQ   2048
#define DMODEL  512
#define NHEADS  8
#define DH      64
#define NEG_INF -1.0e9f

typedef __attribute__((ext_vector_type(8))) short short8;
typedef __attribute__((ext_vector_type(4))) float f32x4;
typedef unsigned int u32;
typedef unsigned short u16;

// cheap bf16 pack: round-half-up, error <= 2^-9 rel. No NaNs in this pipeline.
__device__ __forceinline__ u16 f2bf(float f) {
    union { float f; u32 u; } w; w.f = f;
    return (u16)((w.u + 0x8000u) >> 16);
}

// async global->LDS, 16B per lane. LDS dest must be wave-uniform base + lane*16.
__device__ __forceinline__ void async_load16(const u16* g, u16* l) {
    __builtin_amdgcn_global_load_lds(
        (const __attribute__((address_space(1))) u32*)(const void*)g,
        (__attribute__((address_space(3))) u32*)(void*)l, 16, 0, 0);
}

// ---------------------------------------------------------------------------
// fused fp32->bf16 casts (x + 4 weights) + span-loss scalar. 5120 blocks.
// ---------------------------------------------------------------------------
__global__ void cast_all(const float* __restrict__ x,  const float* __restrict__ wq,
                         const float* __restrict__ wk, const float* __restrict__ wv,
                         const float* __restrict__ wo, const float* __restrict__ sp,
                         u16* __restrict__ xb,  u16* __restrict__ wqb,
                         u16* __restrict__ wkb, u16* __restrict__ wvb,
                         u16* __restrict__ wob, float* __restrict__ loss_out)
{
    const int bid = blockIdx.x;
    const float* src; u16* dst; int i;
    if (bid < 4096) { src = x; dst = xb; i = bid * 256 + threadIdx.x; }
    else {
        const int wsel = (bid - 4096) >> 8;
        src = (wsel == 0) ? wq : (wsel == 1) ? wk : (wsel == 2) ? wv : wo;
        dst = (wsel == 0) ? wqb : (wsel == 1) ? wkb : (wsel == 2) ? wvb : wob;
        i = ((bid - 4096) & 255) * 256 + threadIdx.x;
    }
    float4 v = ((const float4*)src)[i];
    ushort4 o;
    o.x = f2bf(v.x); o.y = f2bf(v.y); o.z = f2bf(v.z); o.w = f2bf(v.w);
    ((ushort4*)dst)[i] = o;
    if (bid == 5119 && threadIdx.x == 0) {
        float s = 0.0f;
        for (int h = 0; h < NHEADS; ++h)
            s += fminf(fmaxf(sp[h], 0.0f), 1.0f);
        loss_out[0] = 2e-4f * (s * 0.125f);
    }
}

// ---------------------------------------------------------------------------
// bf16 MFMA GEMM (R5 version: async global_load_lds staging, NO occupancy
// clamp - the (256,3) bound in R6 caused 170 MB/dispatch of scratch spill).
// z=0/1: bf16 (B,H,T,DH); z=2: bf16 (B,H,DH,T) (V^T); scatter=0: fp32 M x 512.
// ---------------------------------------------------------------------------
__global__ __launch_bounds__(256)
void gemm_bf16(const u16* __restrict__ A,
               const u16* __restrict__ W0, const u16* __restrict__ W1,
               const u16* __restrict__ W2,
               u16* __restrict__ Cb0, u16* __restrict__ Cb1,
               u16* __restrict__ Cb2,
               float* __restrict__ Cf, int scatter)
{
    constexpr int K = 512, BK = 64;
    const u16* W  = (blockIdx.z == 0) ? W0 : (blockIdx.z == 1) ? W1 : W2;
    u16*       Cb = (blockIdx.z == 0) ? Cb0 : (blockIdx.z == 1) ? Cb1 : Cb2;

    __shared__ __align__(16) u16 smem[16384];   // 32 KB: As|Bs, reused by epilogue
    u16* As = smem;
    u16* Bs = smem + 8192;

    const int t    = threadIdx.x;
    const int lane = t & 63;
    const int wave = t >> 6;
    const int wm   = wave >> 1, wn = wave & 1;
    const int m0   = blockIdx.x * 128, n0 = blockIdx.y * 128;

    const int srow = t >> 3;
    const int kb   = (t & 7) ^ (srow & 7);
    const u16* gA = A + (size_t)(m0 + srow) * K + kb * 8;
    const u16* gW = W + (size_t)(n0 + srow) * K + kb * 8;

    const int rA = wm * 64 + (lane & 15);
    const int rB = wn * 64 + (lane & 15);
    const int kq = lane >> 4;
    const int offA0 = rA * BK + ((kq      ^ (rA & 7)) * 8);
    const int offA1 = rA * BK + (((4 + kq) ^ (rA & 7)) * 8);
    const int offB0 = rB * BK + ((kq      ^ (rB & 7)) * 8);
    const int offB1 = rB * BK + (((4 + kq) ^ (rB & 7)) * 8);

    f32x4 acc[4][4];
#pragma unroll
    for (int it = 0; it < 4; ++it)
#pragma unroll
        for (int jt = 0; jt < 4; ++jt) acc[it][jt] = (f32x4)0.0f;

    for (int k0 = 0; k0 < K; k0 += BK) {
        __syncthreads();
#pragma unroll
        for (int i = 0; i < 4; ++i) {
            async_load16(gA + k0 + i * (32 * K), As + t * 8 + i * 2048);
            async_load16(gW + k0 + i * (32 * K), Bs + t * 8 + i * 2048);
        }
        __syncthreads();

        short8 af[4][2], bfr[4][2];
#pragma unroll
        for (int it = 0; it < 4; ++it) {
            af[it][0]  = *(const short8*)(As + offA0 + it * 16 * BK);
            af[it][1]  = *(const short8*)(As + offA1 + it * 16 * BK);
            bfr[it][0] = *(const short8*)(Bs + offB0 + it * 16 * BK);
            bfr[it][1] = *(const short8*)(Bs + offB1 + it * 16 * BK);
        }
#pragma unroll
        for (int it = 0; it < 4; ++it)
#pragma unroll
            for (int jt = 0; jt < 4; ++jt) {
                acc[it][jt] = __builtin_amdgcn_mfma_f32_16x16x32_bf16(
                    af[it][0], bfr[jt][0], acc[it][jt], 0, 0, 0);
                acc[it][jt] = __builtin_amdgcn_mfma_f32_16x16x32_bf16(
                    af[it][1], bfr[jt][1], acc[it][jt], 0, 0, 0);
            }
    }

    const int r0 = (lane >> 4) * 4;
    const int cl = lane & 15;

    if (scatter) {
        const bool vt_mode = (blockIdx.z == 2);
        constexpr int P = 136;
#pragma unroll
        for (int rnd = 0; rnd < 2; ++rnd) {
            __syncthreads();
#pragma unroll
            for (int s = 0; s < 2; ++s) {
                const int it = rnd * 2 + s;
                const int lrow = wm * 32 + s * 16 + r0;
#pragma unroll
                for (int jt = 0; jt < 4; ++jt) {
                    const int cc = wn * 64 + jt * 16 + cl;
#pragma unroll
                    for (int r = 0; r < 4; ++r)
                        smem[(lrow + r) * P + cc] = f2bf(acc[it][jt][r]);
                }
            }
            __syncthreads();
            if (!vt_mode) {
                const int lrow2 = t >> 2;
                const int h2    = (t >> 1) & 1;
                const int dhalf = t & 1;
                const int grow  = m0 + (lrow2 >> 5) * 64 + rnd * 32 + (lrow2 & 31);
                const int b     = grow >> 11, tt = grow & 2047;
                const int h     = (n0 >> 6) + h2;
                u16* dst = Cb + ((size_t)((b * NHEADS + h) * T_SEQ + tt)) * DH + dhalf * 32;
                const u16* srcl = smem + lrow2 * P + h2 * 64 + dhalf * 32;
#pragma unroll
                for (int i = 0; i < 4; ++i)
                    ((uint4*)dst)[i] = *(const uint4*)(srcl + i * 8);
            } else {
                const int hd   = t >> 1;
                const int run  = t & 1;
                const int h    = (n0 >> 6) + (hd >> 6);
                const int d    = hd & 63;
                const int tb   = m0 + run * 64 + rnd * 32;
                const int b    = tb >> 11;
                u16* dst = Cb + (((size_t)(b * NHEADS + h) * DH + d) << 11) + (tb & 2047);
                union { uint4 v[4]; u16 s[32]; } pk;
#pragma unroll
                for (int i = 0; i < 32; ++i)
                    pk.s[i] = smem[(run * 32 + i) * P + hd];
#pragma unroll
                for (int i = 0; i < 4; ++i)
                    ((uint4*)dst)[i] = pk.v[i];
            }
        }
    } else {
#pragma unroll
        for (int it = 0; it < 4; ++it) {
#pragma unroll
            for (int r = 0; r < 4; ++r) {
                const int row = m0 + wm * 64 + it * 16 + r0 + r;
#pragma unroll
                for (int jt = 0; jt < 4; ++jt) {
                    const int col = n0 + wn * 64 + jt * 16 + cl;
                    Cf[(size_t)row * DMODEL + col] = acc[it][jt][r];
                }
            }
        }
    }
}

// ---------------------------------------------------------------------------
// Barrier-free MFMA windowed flash attention. One WAVE = one 16-query tile.
// K/V MFMA B-fragments loaded DIRECTLY from global (L2-resident via XCD pin).
// launch_bounds (64,2): VGPR cap 256 (the R6 (64,4) clamp = 128 forced spills).
// ---------------------------------------------------------------------------
__global__ __launch_bounds__(64, 2)
void attn_wave(const u16* __restrict__ Q, const u16* __restrict__ K,
               const u16* __restrict__ Vt, const float* __restrict__ span_params,
               u16* __restrict__ out)
{
    __shared__ __align__(16) u16 Ps[16 * 72];   // P [q][key], pitch 72

    const int lane = threadIdx.x;
    const int nl   = lane & 15;
    const int quad = lane >> 4;
    const int xi   = blockIdx.x;
    const int b    = xi >> 3;
    const int h    = ((xi & 7) + 5 * b) & 7;
    const int bh   = b * NHEADS + h;
    const int q0   = blockIdx.y * 16;

    const u16* Qh = Q  + (size_t)bh * (T_SEQ * DH);
    const u16* Kh = K  + (size_t)bh * (T_SEQ * DH);
    const u16* Vh = Vt + (size_t)bh * (DH * T_SEQ);

    float span = span_params[h];
    span = fminf(fmaxf(span, 0.0f), 1.0f);
    const float eff_span = span * 512.0f;
    const int wspan = (int)(eff_span + 1.0f) + 1;

    // Q A-fragments in registers for the whole kernel
    short8 qf0 = *(const short8*)(Qh + (size_t)(q0 + nl) * DH + quad * 8);
    short8 qf1 = *(const short8*)(Qh + (size_t)(q0 + nl) * DH + 32 + quad * 8);

    f32x4 o[4];
    float m_r[4], l_r[4];
#pragma unroll
    for (int d = 0; d < 4; ++d) o[d] = (f32x4)0.0f;
#pragma unroll
    for (int r = 0; r < 4; ++r) { m_r[r] = -1.0e30f; l_r[r] = 0.0f; }

    int j_lo = q0 - wspan;
    if (j_lo < 0) j_lo = 0;
    j_lo &= ~63;
    const int j_hi = (q0 + 15) & ~63;

    for (int j0 = j_lo; j0 <= j_hi; j0 += 64) {
        // ---- tile activity (wave-uniform) ----
        bool any[4];
#pragma unroll
        for (int n = 0; n < 4; ++n) {
            const int jn = j0 + n * 16;
            any[n] = (jn <= q0 + 15) &&
                     ((float)(q0 - jn - 15) < eff_span + 1.0f);   // some R>0
        }

        // ---- S = Q K^T: B-frags straight from global ----
        f32x4 s[4];
#pragma unroll
        for (int n = 0; n < 4; ++n) {
            s[n] = (f32x4)0.0f;
            if (any[n]) {
                const u16* kp = Kh + (size_t)(j0 + n * 16 + nl) * DH + quad * 8;
                short8 b0 = *(const short8*)kp;
                short8 b1 = *(const short8*)(kp + 32);
                s[n] = __builtin_amdgcn_mfma_f32_16x16x32_bf16(qf0, b0, s[n], 0, 0, 0);
                s[n] = __builtin_amdgcn_mfma_f32_16x16x32_bf16(qf1, b1, s[n], 0, 0, 0);
            }
        }

        // ---- V B-frags: issue early so latency hides behind softmax ----
        const bool kf0 = any[0] | any[1];
        const bool kf1 = any[2] | any[3];
        short8 vb0[4], vb1[4];
#pragma unroll
        for (int d = 0; d < 4; ++d) {
            const u16* vp = Vh + (size_t)(d * 16 + nl) * T_SEQ + j0 + quad * 8;
            if (kf0) vb0[d] = *(const short8*)vp;
            if (kf1) vb1[d] = *(const short8*)(vp + 32);
        }

        // ---- mask + row max, 3-way tile classification (wave-uniform) ----
        float tmax[4] = {-1.0e30f, -1.0e30f, -1.0e30f, -1.0e30f};
#pragma unroll
        for (int n = 0; n < 4; ++n) {
            if (!any[n]) continue;
            const int jn = j0 + n * 16;
            const bool causal_b = (jn + 15 > q0);
            const bool span_b   = ((float)(q0 + 15 - jn) > eff_span - 3.0f);
            if (!causal_b && !span_b) {
#pragma unroll
                for (int r = 0; r < 4; ++r) {
                    const float sv = s[n][r] * 0.125f;
                    s[n][r] = sv;
                    tmax[r] = fmaxf(tmax[r], sv);
                }
            } else if (!span_b) {
#pragma unroll
                for (int r = 0; r < 4; ++r) {
                    const int dist = (q0 + quad * 4 + r) - (jn + nl);
                    const float sv = (dist >= 0) ? s[n][r] * 0.125f : NEG_INF;
                    s[n][r] = sv;
                    tmax[r] = fmaxf(tmax[r], sv);
                }
            } else {
#pragma unroll
                for (int r = 0; r < 4; ++r) {
                    const int dist = (q0 + quad * 4 + r) - (jn + nl);
                    float sv = NEG_INF;
                    if (dist >= 0) {
                        float xv = eff_span - (float)dist;
                        float R  = fminf(fmaxf((xv + 1.0f) * 0.25f, 0.0f), 1.0f);
                        if (R > 0.0f)
                            sv = s[n][r] * 0.125f +
                                 ((R < 1.0f) ? __logf(R + 1e-10f) : 0.0f);
                    }
                    s[n][r] = sv;
                    tmax[r] = fmaxf(tmax[r], sv);
                }
            }
        }

        // ---- online softmax state ----
        float alpha[4];
#pragma unroll
        for (int r = 0; r < 4; ++r) {
            float t = tmax[r];
            t = fmaxf(t, __shfl_xor(t, 1));
            t = fmaxf(t, __shfl_xor(t, 2));
            t = fmaxf(t, __shfl_xor(t, 4));
            t = fmaxf(t, __shfl_xor(t, 8));
            const float m_new = fmaxf(m_r[r], t);
            alpha[r] = __expf(m_r[r] - m_new);
            m_r[r] = m_new;
        }

        // ---- P = exp(S - m) -> bf16 LDS (in-wave round trip, no barrier) ----
        float psum[4] = {0.0f, 0.0f, 0.0f, 0.0f};
#pragma unroll
        for (int n = 0; n < 4; ++n) {
            if (any[n]) {
#pragma unroll
                for (int r = 0; r < 4; ++r) {
                    const float pv = __expf(s[n][r] - m_r[r]);
                    psum[r] += pv;
                    Ps[(quad * 4 + r) * 72 + n * 16 + nl] = f2bf(pv);
                }
            } else {
#pragma unroll
                for (int r = 0; r < 4; ++r)
                    Ps[(quad * 4 + r) * 72 + n * 16 + nl] = 0;
            }
        }
#pragma unroll
        for (int r = 0; r < 4; ++r) {
            float ps = psum[r];
            ps += __shfl_xor(ps, 1);
            ps += __shfl_xor(ps, 2);
            ps += __shfl_xor(ps, 4);
            ps += __shfl_xor(ps, 8);
            l_r[r] = l_r[r] * alpha[r] + ps;
#pragma unroll
            for (int d = 0; d < 4; ++d) o[d][r] *= alpha[r];
        }

        // ---- O += P V ----
        const u16* pb = Ps + nl * 72;
        short8 a0 = *(const short8*)(pb + quad * 8);
        short8 a1 = *(const short8*)(pb + 32 + quad * 8);
#pragma unroll
        for (int d = 0; d < 4; ++d) {
            if (kf0)
                o[d] = __builtin_amdgcn_mfma_f32_16x16x32_bf16(a0, vb0[d], o[d], 0, 0, 0);
            if (kf1)
                o[d] = __builtin_amdgcn_mfma_f32_16x16x32_bf16(a1, vb1[d], o[d], 0, 0, 0);
        }
    }

    // ---- epilogue ----
#pragma unroll
    for (int r = 0; r < 4; ++r) {
        const int qg = q0 + quad * 4 + r;
        const float inv_l = 1.0f / l_r[r];
        u16* op = out + (size_t)(b * T_SEQ + qg) * DMODEL + h * 64;
#pragma unroll
        for (int d = 0; d < 4; ++d)
            op[d * 16 + nl] = f2bf(o[d][r] * inv_l);
    }
}

extern "C" void kernel_launch(void* const* d_in, const int* in_sizes, int n_in,
                              void* d_out, int out_size, void* d_ws, size_t ws_size,
                              hipStream_t stream)
{
    (void)in_sizes; (void)n_in; (void)out_size; (void)ws_size;
    const float* x  = (const float*)d_in[0];
    const float* wq = (const float*)d_in[1];
    const float* wk = (const float*)d_in[2];
    const float* wv = (const float*)d_in[3];
    const float* wo = (const float*)d_in[4];
    const float* sp = (const float*)d_in[5];
    float* out = (float*)d_out;

    const size_t elems = (size_t)4 * T_SEQ * DMODEL;  // 4,194,304
    u16* xb  = (u16*)d_ws;
    u16* Qb  = xb  + elems;
    u16* Kb  = Qb  + elems;
    u16* Vtb = Kb  + elems;
    u16* Ab  = Vtb + elems;
    u16* wqb = Ab  + elems;
    u16* wkb = wqb + 262144;
    u16* wvb = wkb + 262144;
    u16* wob = wvb + 262144;

    // casts + loss (one launch)
    cast_all<<<5120, 256, 0, stream>>>(x, wq, wk, wv, wo, sp,
                                       xb, wqb, wkb, wvb, wob, out + elems);
    // Q,K,V projections (V written directly transposed)
    gemm_bf16<<<dim3(64, 4, 3), 256, 0, stream>>>(
        xb, wqb, wkb, wvb, Qb, Kb, Vtb, nullptr, 1);
    // barrier-free MFMA windowed flash attention (1 wave = 16 q)
    attn_wave<<<dim3(32, 128), 64, 0, stream>>>(Qb, Kb, Vtb, sp, Ab);
    // output projection (fp32 out)
    gemm_bf16<<<dim3(64, 4, 1), 256, 0, stream>>>(
        Ab, wob, wob, wob, nullptr, nullptr, nullptr, out, 0);
}